// Round 1
// baseline (72.567 us; speedup 1.0000x reference)
//
#include <hip/hip_runtime.h>

// Tropical (max-plus) matmul: out[n,m] = max_k(|x[n,k]| + |w[m,k]|)
// N=1024, K=256, M=1024, fp32 in/out.
//
// Round 3: LDS-traffic fix. R2 (2x2 blocking) read 4 B of LDS per output*k
// (1.07 GB total -> >=14 us at the 69-78 TB/s LDS ceiling) and paid 8
// __syncthreads. Now: 64x64 tile, 4x4 outputs/thread (2 B LDS per output*k,
// halved), full K=256 resident in 128 KB LDS -> ONE barrier, 128
// straight-line k-pair iterations, 16 independent max-chains.
// Grid 256 blocks = 1 block/CU (LDS-capped), 4 waves/CU.
//
// LDS layout: kp-major [kp][row] in v2f units so compute reads are b128
// (4 rows x 1 k-pair per side). The staging transpose (row-major global ->
// kp-major LDS) would be 8-way bank conflicted; rows are XOR-swizzled with
// ((kp&3)<<2) (bits 2-3 only, preserves b128 4-row contiguity) -> 4-way,
// one-time. With unroll-4 the swizzle is a compile-time offset in the loop.

typedef float v2f __attribute__((ext_vector_type(2)));
typedef float v4f __attribute__((ext_vector_type(4)));

constexpr int K    = 256;
constexpr int M    = 1024;
constexpr int TILE = 64;
constexpr int KP   = K / 2;   // 128 k-pair rows
constexpr int P    = TILE;    // 64 v2f (512 B) per kp row, no pad (swizzled)

__global__ void __launch_bounds__(256, 1)
tropical_kernel(const float* __restrict__ xg, const float* __restrict__ wg,
                float* __restrict__ outg)
{
    __shared__ __align__(16) v2f xs[KP * P];   // 64 KB
    __shared__ __align__(16) v2f ws[KP * P];   // 64 KB

    const int tid = threadIdx.x;
    const int tx  = tid & 15;          // m-side: 4 cols at 4*tx
    const int ty  = tid >> 4;          // n-side: 4 rows at 4*ty
    const int bn  = (int)(blockIdx.x >> 4) * TILE;
    const int bm  = (int)(blockIdx.x & 15) * TILE;

    // Staging: thread covers rows {r0, r0+32}, quads q = l + 8*i.
    // Global: 8 lanes x 16 B contiguous = 128-B segments (coalesced).
    const int r0 = tid >> 3;           // 0..31
    const int l  = tid & 7;            // 0..7

    const float* xr0 = xg + (bn + r0) * K;
    const float* xr1 = xg + (bn + r0 + 32) * K;
    const float* wr0 = wg + (bm + r0) * K;
    const float* wr1 = wg + (bm + r0 + 32) * K;

#pragma unroll
    for (int i = 0; i < 8; ++i) {
        const int q  = l + 8 * i;      // quad 0..63
        const int kp = 2 * q;
        v4f a = *(const v4f*)(xr0 + 4 * q);
        v4f b = *(const v4f*)(xr1 + 4 * q);
        v4f c = *(const v4f*)(wr0 + 4 * q);
        v4f d = *(const v4f*)(wr1 + 4 * q);
        const int s0 = ((kp    ) & 3) << 2;   // row-slot swizzle for kp
        const int s1 = ((kp + 1) & 3) << 2;   // ... for kp+1
        xs[(kp    ) * P + ((r0     ) ^ s0)] = (v2f){fabsf(a.x), fabsf(a.y)};
        xs[(kp + 1) * P + ((r0     ) ^ s1)] = (v2f){fabsf(a.z), fabsf(a.w)};
        xs[(kp    ) * P + ((r0 + 32) ^ s0)] = (v2f){fabsf(b.x), fabsf(b.y)};
        xs[(kp + 1) * P + ((r0 + 32) ^ s1)] = (v2f){fabsf(b.z), fabsf(b.w)};
        ws[(kp    ) * P + ((r0     ) ^ s0)] = (v2f){fabsf(c.x), fabsf(c.y)};
        ws[(kp + 1) * P + ((r0     ) ^ s1)] = (v2f){fabsf(c.z), fabsf(c.w)};
        ws[(kp    ) * P + ((r0 + 32) ^ s0)] = (v2f){fabsf(d.x), fabsf(d.y)};
        ws[(kp + 1) * P + ((r0 + 32) ^ s1)] = (v2f){fabsf(d.z), fabsf(d.w)};
    }

    __syncthreads();   // the only barrier

    // Sums are >= 0, so 0 is a safe max-identity.
    float acc[4][4];
#pragma unroll
    for (int a2 = 0; a2 < 4; ++a2)
#pragma unroll
        for (int b2 = 0; b2 < 4; ++b2) acc[a2][b2] = 0.f;

    // Pre-swizzled in-row v2f offsets for the 4 kp phases (kp&3 is a
    // compile-time constant inside the unroll-4 body -> static indexing).
    int xo[4], wo[4];
#pragma unroll
    for (int c4 = 0; c4 < 4; ++c4) {
        xo[c4] = (4 * ty) ^ (c4 << 2);
        wo[c4] = (4 * tx) ^ (c4 << 2);
    }

#pragma unroll 4
    for (int kp = 0; kp < KP; ++kp) {
        const v2f* xrow = &xs[kp * P];
        const v2f* wrow = &ws[kp * P];
        const int xof = xo[kp & 3];
        const int wof = wo[kp & 3];
        v4f x01 = *(const v4f*)(xrow + xof);       // rows 4ty,4ty+1 (swz)
        v4f x23 = *(const v4f*)(xrow + xof + 2);   // rows 4ty+2,4ty+3
        v4f w01 = *(const v4f*)(wrow + wof);
        v4f w23 = *(const v4f*)(wrow + wof + 2);

        v2f xa[4] = {{x01.x, x01.y}, {x01.z, x01.w},
                     {x23.x, x23.y}, {x23.z, x23.w}};
        v2f wa[4] = {{w01.x, w01.y}, {w01.z, w01.w},
                     {w23.x, w23.y}, {w23.z, w23.w}};

#pragma unroll
        for (int a2 = 0; a2 < 4; ++a2)
#pragma unroll
            for (int b2 = 0; b2 < 4; ++b2) {
                v2f s = xa[a2] + wa[b2];                      // v_pk_add_f32
                acc[a2][b2] = fmaxf(acc[a2][b2], fmaxf(s.x, s.y)); // v_max3_f32
            }
    }

    const int n0 = bn + 4 * ty;
    const int m0 = bm + 4 * tx;
#pragma unroll
    for (int j = 0; j < 4; ++j) {
        v4f o = {acc[j][0], acc[j][1], acc[j][2], acc[j][3]};
        *(v4f*)(outg + (n0 + j) * M + m0) = o;   // 16 lanes x 16 B contiguous
    }
}

extern "C" void kernel_launch(void* const* d_in, const int* in_sizes, int n_in,
                              void* d_out, int out_size, void* d_ws, size_t ws_size,
                              hipStream_t stream)
{
    const float* x = (const float*)d_in[0];   // [1024, 256]
    const float* w = (const float*)d_in[1];   // [1024, 256]
    float* out = (float*)d_out;               // [1024, 1024]

    dim3 grid(256);    // 16 x 16 tiles of 64x64, 1 block/CU
    dim3 block(256);
    tropical_kernel<<<grid, block, 0, stream>>>(x, w, out);
}